// Round 11
// baseline (555.656 us; speedup 1.0000x reference)
//
#include <hip/hip_runtime.h>

#define DIM 256
#define RPB 32            // dst rows per bucket
#define LOG_RPB 5
#define NG 8              // XCD groups: g=(e>>8)&7 == blockIdx&7 (grid%8==0)
#define BATCH 16
#define CAP 128           // slab capacity per (g,bucket) cell; Poisson(<=40) -> 14 sigma
#define BCAP 512          // edges per bucket; Poisson(<=320) -> 10.7 sigma
#define PC_B 3072         // place_conv blocks (two roles of 1536; each %8==0)

typedef float f32x4 __attribute__((ext_vector_type(4)));
typedef unsigned int u32;
typedef unsigned short u16;

__device__ __forceinline__ u16 f32_to_bf16_rne(float f) {
    u32 u = __float_as_uint(f);
    return (u16)((u + 0x7FFFu + ((u >> 16) & 1u)) >> 16);
}

// ---------- fused slab placement (XCD-local) + f32->bf16 convert (round-8, proven) ----
// Half the blocks place (latency/atomic-bound), half convert (BW-bound); orthogonal
// resources overlap. Place-role rank `sub` keeps sub&7 == blockIdx&7 == XCD, so cell
// (g=(e>>8)&7) counters/slabs are only touched by XCD g.

__global__ void place_conv(const int* __restrict__ sA, const int* __restrict__ dA,
                           const int* __restrict__ sB, const int* __restrict__ dB,
                           int* __restrict__ cnt, u32* __restrict__ binned,
                           int TBc, int NBA_, int E1, int Etot,
                           const float* __restrict__ xin, u16* __restrict__ xbf,
                           long long n4) {
    int sub = ((int)blockIdx.x >> 4) * 8 + ((int)blockIdx.x & 7);  // role-local rank
    int half = (int)gridDim.x >> 1;                                // 1536, %8==0
    if ((((int)blockIdx.x >> 3) & 1) == 0) {
        // ---- place role ----
        int stride = half * (int)blockDim.x;                       // stride>>8 %8==0: g invariant
        for (int e = sub * (int)blockDim.x + (int)threadIdx.x; e < Etot; e += stride) {
            int g = (e >> 8) & (NG - 1);                           // == sub&7 == this XCD
            int s, d, b;
            if (e < E1) {
                s = __builtin_nontemporal_load(sA + e);
                d = __builtin_nontemporal_load(dA + e);
                b = d >> LOG_RPB;
            } else {
                int e2 = e - E1;
                s = __builtin_nontemporal_load(sB + e2);
                d = __builtin_nontemporal_load(dB + e2);
                b = NBA_ + (d >> LOG_RPB);
            }
            int cell = g * TBc + b;
            int old = atomicAdd(&cnt[cell], 1);                    // XCD-private counter
            if (old < CAP)
                binned[(long long)cell * CAP + old] = ((u32)s << LOG_RPB) | (u32)(d & (RPB - 1));
        }
    } else {
        // ---- convert role: x_paper f32 -> bf16 ----
        long long stride = (long long)half * blockDim.x;
        for (long long i = (long long)sub * blockDim.x + threadIdx.x; i < n4; i += stride) {
            f32x4 v = __builtin_nontemporal_load((const f32x4*)xin + i);
            ushort4 o;
            o.x = f32_to_bf16_rne(v.x); o.y = f32_to_bf16_rne(v.y);
            o.z = f32_to_bf16_rne(v.z); o.w = f32_to_bf16_rne(v.w);
            *((ushort4*)xbf + i) = o;                              // re-read by gather1: cached
        }
    }
}

// ---------- gather hop: one block per bucket. Sort own bucket into LDS, then gather
// own 32 rows. Self-contained: rows of bucket b only read bucket-b edges. ----------

template <bool DBF>
__global__ void __launch_bounds__(256)
gather_hop(const u32* __restrict__ binned, const int* __restrict__ cnt,
           const u16* __restrict__ xv, void* __restrict__ outv,
           int TBc, int bucket_base, int n) {
    __shared__ int sed[BCAP];          // src ids, grouped by local row
    __shared__ int rp[RPB + 1];        // local row offsets into sed
    __shared__ int c[RPB];
    __shared__ int cur[RPB];

    int tid = (int)threadIdx.x;
    int b = bucket_base + (int)blockIdx.x;

    // --- phase 1: histogram of local-row ids over the 8 XCD slabs ---
    if (tid < RPB) c[tid] = 0;
    __syncthreads();
#pragma unroll
    for (int g = 0; g < NG; ++g) {
        int cell = g * TBc + b;
        int m = cnt[cell]; m = (m < CAP) ? m : CAP;
        long long base = (long long)cell * CAP;
        for (int i = tid; i < m; i += 256)
            atomicAdd(&c[binned[base + i] & (RPB - 1)], 1);
    }
    __syncthreads();
    // --- phase 2: tiny serial prefix (32 entries) ---
    if (tid == 0) {
        int run = 0;
        for (int r = 0; r < RPB; ++r) { cur[r] = run; rp[r] = run; run += c[r]; }
        rp[RPB] = run;
    }
    __syncthreads();
    // --- phase 3: place src ids grouped by local row (native LDS int atomics) ---
#pragma unroll
    for (int g = 0; g < NG; ++g) {
        int cell = g * TBc + b;
        int m = cnt[cell]; m = (m < CAP) ? m : CAP;
        long long base = (long long)cell * CAP;
        for (int i = tid; i < m; i += 256) {
            u32 e = binned[base + i];
            int pos = atomicAdd(&cur[e & (RPB - 1)], 1);
            sed[pos] = (int)(e >> LOG_RPB);
        }
    }
    __syncthreads();

    // --- phase 4: gather 32 rows; wave w owns rows w, w+4, ... ---
    int lane = tid & 63, w = tid >> 6;
    int row0 = (int)blockIdx.x * RPB;
    for (int rr = w; rr < RPB; rr += 4) {
        int row = row0 + rr;
        if (row >= n) break;
        int beg = rp[rr];
        int end = rp[rr + 1];
        f32x4 acc = { 0.f, 0.f, 0.f, 0.f };
        for (int i = beg; i < end; i += BATCH) {
            int m = end - i;
            m = (m < BATCH) ? m : BATCH;                  // wave-uniform
            uint2 vv[BATCH];
#pragma unroll
            for (int j = 0; j < BATCH; ++j) {             // issue: m loads back-to-back
                if (j >= m) break;                        // wave-uniform early exit
                int s = sed[i + j];                       // LDS broadcast
                vv[j] = *((const uint2*)(xv + (long long)s * DIM) + lane);
            }
#pragma unroll
            for (int j = 0; j < BATCH; ++j) {             // commit: plain packed adds
                if (j >= m) break;                        // wave-uniform early exit
                f32x4 add = { __uint_as_float(vv[j].x << 16),
                              __uint_as_float(vv[j].x & 0xFFFF0000u),
                              __uint_as_float(vv[j].y << 16),
                              __uint_as_float(vv[j].y & 0xFFFF0000u) };
                acc += add;
            }
        }
        float ax = fmaxf(acc.x, 0.f), ay = fmaxf(acc.y, 0.f);
        float az = fmaxf(acc.z, 0.f), aw = fmaxf(acc.w, 0.f);
        if (DBF) {
            ushort4 o;
            o.x = f32_to_bf16_rne(ax); o.y = f32_to_bf16_rne(ay);
            o.z = f32_to_bf16_rne(az); o.w = f32_to_bf16_rne(aw);
            *((ushort4*)outv + (long long)row * (DIM / 4) + lane) = o;  // re-read next hop
        } else {
            f32x4 o = { ax, ay, az, aw };
            __builtin_nontemporal_store(o, (f32x4*)outv + (long long)row * (DIM / 4) + lane);
        }
    }
}

// ---------- host ----------

extern "C" void kernel_launch(void* const* d_in, const int* in_sizes, int n_in,
                              void* d_out, int out_size, void* d_ws, size_t ws_size,
                              hipStream_t stream) {
    const float* x_paper = (const float*)d_in[0];
    const int* e_pa_src = (const int*)d_in[2];
    const int* e_pa_dst = (const int*)d_in[3];
    const int* e_ap_src = (const int*)d_in[4];
    const int* e_ap_dst = (const int*)d_in[5];

    const int nA = in_sizes[1] / DIM;         // 100000 authors (hop-1 dst)
    const int nB = in_sizes[0] / DIM;         // 200000 papers  (hop-2 dst)
    const int E1 = in_sizes[2];               // 1000000 (paper->author)
    const int E2 = in_sizes[4];               // 1000000 (author->paper)
    const int Etot = E1 + E2;

    const int NBA = (nA + RPB - 1) / RPB;     // 3125
    const int NBB = (nB + RPB - 1) / RPB;     // 6250
    const int TBc = NBA + NBB;                // 9375

    // ---- workspace (~192 MB) ----
    size_t off = 0;
    auto alloc = [&](size_t bytes) { size_t o = off; off += (bytes + 255) & ~(size_t)255; return o; };
    size_t o_xpbf   = alloc((size_t)nB * DIM * sizeof(u16));          // 102.4 MB
    size_t o_xa1    = alloc((size_t)nA * DIM * sizeof(u16));          // 51.2 MB
    size_t o_cnt    = alloc((size_t)NG * TBc * sizeof(int));          // 0.3 MB
    size_t o_binned = alloc((size_t)NG * TBc * CAP * sizeof(u32));    // 38.4 MB
    (void)ws_size;

    char* ws = (char*)d_ws;
    u16* xpbf   = (u16*)(ws + o_xpbf);
    u16* x_a1   = (u16*)(ws + o_xa1);
    int* cnt    = (int*)(ws + o_cnt);
    u32* binned = (u32*)(ws + o_binned);
    float* x_p2 = (float*)d_out;

    hipMemsetAsync(cnt, 0, (size_t)NG * TBc * sizeof(int), stream);

    long long n4 = (long long)nB * DIM / 4;
    place_conv<<<PC_B, 256, 0, stream>>>(
        e_pa_src, e_pa_dst, e_ap_src, e_ap_dst, cnt, binned,
        TBc, NBA, E1, Etot, x_paper, xpbf, n4);

    // hop 1: paper -> author, out = bf16(relu(sum)); each block sorts+gathers its bucket
    gather_hop<true><<<NBA, 256, 0, stream>>>(binned, cnt, xpbf, x_a1, TBc, 0, nA);

    // hop 2: author -> paper, out = f32 relu(sum), NT stores
    gather_hop<false><<<NBB, 256, 0, stream>>>(binned, cnt, x_a1, x_p2, TBc, NBA, nB);
}

// Round 12
// 513.322 us; speedup vs baseline: 1.0825x; 1.0825x over previous
//
#include <hip/hip_runtime.h>

#define DIM 256
#define RPB 32            // dst rows per bucket
#define LOG_RPB 5
#define NG 8              // XCD groups: g=(e>>8)&7 == blockIdx&7 (grid%8==0)
#define CAP 128           // slab capacity per (g,bucket) cell; Poisson(<=40) -> 14 sigma
#define BCAP 512          // edges per bucket; Poisson(<=320) -> 10.7 sigma
#define PC_B 3072         // place_conv blocks (two roles of 1536; each %8==0)

typedef float f32x4 __attribute__((ext_vector_type(4)));
typedef unsigned int u32;
typedef unsigned short u16;

__device__ __forceinline__ u16 f32_to_bf16_rne(float f) {
    u32 u = __float_as_uint(f);
    return (u16)((u + 0x7FFFu + ((u >> 16) & 1u)) >> 16);
}

// ---------- fused slab placement (XCD-local) + f32->bf16 convert (round-8, proven) ----
// Half the blocks place (latency/atomic-bound), half convert (BW-bound); orthogonal
// resources overlap. Place-role rank `sub` keeps sub&7 == blockIdx&7 == XCD, so cell
// (g=(e>>8)&7) counters/slabs are only touched by XCD g.

__global__ void place_conv(const int* __restrict__ sA, const int* __restrict__ dA,
                           const int* __restrict__ sB, const int* __restrict__ dB,
                           int* __restrict__ cnt, u32* __restrict__ binned,
                           int TBc, int NBA_, int E1, int Etot,
                           const float* __restrict__ xin, u16* __restrict__ xbf,
                           long long n4) {
    int sub = ((int)blockIdx.x >> 4) * 8 + ((int)blockIdx.x & 7);  // role-local rank
    int half = (int)gridDim.x >> 1;                                // 1536, %8==0
    if ((((int)blockIdx.x >> 3) & 1) == 0) {
        // ---- place role ----
        int stride = half * (int)blockDim.x;                       // stride>>8 %8==0: g invariant
        for (int e = sub * (int)blockDim.x + (int)threadIdx.x; e < Etot; e += stride) {
            int g = (e >> 8) & (NG - 1);                           // == sub&7 == this XCD
            int s, d, b;
            if (e < E1) {
                s = __builtin_nontemporal_load(sA + e);
                d = __builtin_nontemporal_load(dA + e);
                b = d >> LOG_RPB;
            } else {
                int e2 = e - E1;
                s = __builtin_nontemporal_load(sB + e2);
                d = __builtin_nontemporal_load(dB + e2);
                b = NBA_ + (d >> LOG_RPB);
            }
            int cell = g * TBc + b;
            int old = atomicAdd(&cnt[cell], 1);                    // XCD-private counter
            if (old < CAP)
                binned[(long long)cell * CAP + old] = ((u32)s << LOG_RPB) | (u32)(d & (RPB - 1));
        }
    } else {
        // ---- convert role: x_paper f32 -> bf16 ----
        long long stride = (long long)half * blockDim.x;
        for (long long i = (long long)sub * blockDim.x + threadIdx.x; i < n4; i += stride) {
            f32x4 v = __builtin_nontemporal_load((const f32x4*)xin + i);
            ushort4 o;
            o.x = f32_to_bf16_rne(v.x); o.y = f32_to_bf16_rne(v.y);
            o.z = f32_to_bf16_rne(v.z); o.w = f32_to_bf16_rne(v.w);
            *((ushort4*)xbf + i) = o;                              // re-read by gather1: cached
        }
    }
}

// ---------- gather hop: one block per bucket. Sort own bucket into LDS, then gather
// own 32 rows. ISSUE loop: unconditional clamped (all vv[] defs static -> registers;
// rule #20). COMMIT loop: vv fully defined, so wave-uniform break is safe. ----------

template <int BATCH, bool DBF>
__global__ void __launch_bounds__(256)
gather_hop(const u32* __restrict__ binned, const int* __restrict__ cnt,
           const u16* __restrict__ xv, void* __restrict__ outv,
           int TBc, int bucket_base, int n) {
    __shared__ int sed[BCAP];          // src ids, grouped by local row
    __shared__ int rp[RPB + 1];        // local row offsets into sed
    __shared__ int c[RPB];
    __shared__ int cur[RPB];

    int tid = (int)threadIdx.x;
    int b = bucket_base + (int)blockIdx.x;

    // --- phase 1: histogram of local-row ids over the 8 XCD slabs ---
    if (tid < RPB) c[tid] = 0;
    __syncthreads();
#pragma unroll
    for (int g = 0; g < NG; ++g) {
        int cell = g * TBc + b;
        int m = cnt[cell]; m = (m < CAP) ? m : CAP;
        long long base = (long long)cell * CAP;
        for (int i = tid; i < m; i += 256)
            atomicAdd(&c[binned[base + i] & (RPB - 1)], 1);
    }
    __syncthreads();
    // --- phase 2: tiny serial prefix (32 entries) ---
    if (tid == 0) {
        int run = 0;
        for (int r = 0; r < RPB; ++r) { cur[r] = run; rp[r] = run; run += c[r]; }
        rp[RPB] = run;
    }
    __syncthreads();
    // --- phase 3: place src ids grouped by local row (native LDS int atomics) ---
#pragma unroll
    for (int g = 0; g < NG; ++g) {
        int cell = g * TBc + b;
        int m = cnt[cell]; m = (m < CAP) ? m : CAP;
        long long base = (long long)cell * CAP;
        for (int i = tid; i < m; i += 256) {
            u32 e = binned[base + i];
            int pos = atomicAdd(&cur[e & (RPB - 1)], 1);
            sed[pos] = (int)(e >> LOG_RPB);
        }
    }
    __syncthreads();

    // --- phase 4: gather 32 rows; wave w owns rows w, w+4, ... ---
    int lane = tid & 63, w = tid >> 6;
    int row0 = (int)blockIdx.x * RPB;
    for (int rr = w; rr < RPB; rr += 4) {
        int row = row0 + rr;
        if (row >= n) break;
        int beg = rp[rr];
        int end = rp[rr + 1];
        f32x4 acc = { 0.f, 0.f, 0.f, 0.f };
        for (int i = beg; i < end; i += BATCH) {
            int m = end - i;
            m = (m < BATCH) ? m : BATCH;                  // wave-uniform
            uint2 vv[BATCH];
#pragma unroll
            for (int j = 0; j < BATCH; ++j) {             // issue: ALL defs unconditional
                int jj = (j < m) ? j : (m - 1);           // clamp (dup loads = L1 hits)
                int s = sed[i + jj];                      // LDS broadcast (wave-uniform)
                vv[j] = *((const uint2*)(xv + (long long)s * DIM) + lane);
            }
#pragma unroll
            for (int j = 0; j < BATCH; ++j) {             // commit: vv fully defined,
                if (j >= m) break;                        // wave-uniform break is safe
                f32x4 add = { __uint_as_float(vv[j].x << 16),
                              __uint_as_float(vv[j].x & 0xFFFF0000u),
                              __uint_as_float(vv[j].y << 16),
                              __uint_as_float(vv[j].y & 0xFFFF0000u) };
                acc += add;                               // packed v_pk_add_f32
            }
        }
        float ax = fmaxf(acc.x, 0.f), ay = fmaxf(acc.y, 0.f);
        float az = fmaxf(acc.z, 0.f), aw = fmaxf(acc.w, 0.f);
        if (DBF) {
            ushort4 o;
            o.x = f32_to_bf16_rne(ax); o.y = f32_to_bf16_rne(ay);
            o.z = f32_to_bf16_rne(az); o.w = f32_to_bf16_rne(aw);
            *((ushort4*)outv + (long long)row * (DIM / 4) + lane) = o;  // re-read next hop
        } else {
            f32x4 o = { ax, ay, az, aw };
            __builtin_nontemporal_store(o, (f32x4*)outv + (long long)row * (DIM / 4) + lane);
        }
    }
}

// ---------- host ----------

extern "C" void kernel_launch(void* const* d_in, const int* in_sizes, int n_in,
                              void* d_out, int out_size, void* d_ws, size_t ws_size,
                              hipStream_t stream) {
    const float* x_paper = (const float*)d_in[0];
    const int* e_pa_src = (const int*)d_in[2];
    const int* e_pa_dst = (const int*)d_in[3];
    const int* e_ap_src = (const int*)d_in[4];
    const int* e_ap_dst = (const int*)d_in[5];

    const int nA = in_sizes[1] / DIM;         // 100000 authors (hop-1 dst, mean deg 10)
    const int nB = in_sizes[0] / DIM;         // 200000 papers  (hop-2 dst, mean deg 5)
    const int E1 = in_sizes[2];               // 1000000 (paper->author)
    const int E2 = in_sizes[4];               // 1000000 (author->paper)
    const int Etot = E1 + E2;

    const int NBA = (nA + RPB - 1) / RPB;     // 3125
    const int NBB = (nB + RPB - 1) / RPB;     // 6250
    const int TBc = NBA + NBB;                // 9375

    // ---- workspace (~192 MB) ----
    size_t off = 0;
    auto alloc = [&](size_t bytes) { size_t o = off; off += (bytes + 255) & ~(size_t)255; return o; };
    size_t o_xpbf   = alloc((size_t)nB * DIM * sizeof(u16));          // 102.4 MB
    size_t o_xa1    = alloc((size_t)nA * DIM * sizeof(u16));          // 51.2 MB
    size_t o_cnt    = alloc((size_t)NG * TBc * sizeof(int));          // 0.3 MB
    size_t o_binned = alloc((size_t)NG * TBc * CAP * sizeof(u32));    // 38.4 MB
    (void)ws_size;

    char* ws = (char*)d_ws;
    u16* xpbf   = (u16*)(ws + o_xpbf);
    u16* x_a1   = (u16*)(ws + o_xa1);
    int* cnt    = (int*)(ws + o_cnt);
    u32* binned = (u32*)(ws + o_binned);
    float* x_p2 = (float*)d_out;

    hipMemsetAsync(cnt, 0, (size_t)NG * TBc * sizeof(int), stream);

    long long n4 = (long long)nB * DIM / 4;
    place_conv<<<PC_B, 256, 0, stream>>>(
        e_pa_src, e_pa_dst, e_ap_src, e_ap_dst, cnt, binned,
        TBc, NBA, E1, Etot, x_paper, xpbf, n4);

    // hop 1: paper -> author, out = bf16(relu(sum)); BATCH=16 (mean degree 10)
    gather_hop<16, true><<<NBA, 256, 0, stream>>>(binned, cnt, xpbf, x_a1, TBc, 0, nA);

    // hop 2: author -> paper, out = f32 relu(sum), NT stores; BATCH=8 (mean degree 5)
    gather_hop<8, false><<<NBB, 256, 0, stream>>>(binned, cnt, x_a1, x_p2, TBc, NBA, nB);
}

// Round 13
// 297.731 us; speedup vs baseline: 1.8663x; 1.7241x over previous
//
#include <hip/hip_runtime.h>

#define DIM 256
#define RPB 32            // dst rows per bucket
#define LOG_RPB 5
#define NG 8              // XCD groups: g=(e>>8)&7 == blockIdx&7 (grid%8==0)
#define CAP 128           // slab capacity per (g,bucket) cell; Poisson(<=40) -> 14 sigma
#define BCAP 512          // edges per bucket; Poisson(<=320) -> 10.7 sigma
#define PC_B 3072         // place_conv blocks; 384 groups of 8; group%3==0 -> place (1024),
                          // else convert (2048). Place stride 1024*256: >>8 %8==0 -> g invariant.

typedef float f32x4 __attribute__((ext_vector_type(4)));
typedef unsigned int u32;
typedef unsigned short u16;

__device__ __forceinline__ u16 f32_to_bf16_rne(float f) {
    u32 u = __float_as_uint(f);
    return (u16)((u + 0x7FFFu + ((u >> 16) & 1u)) >> 16);
}

// ---------- fused slab placement (XCD-local) + f32->bf16 convert ----------
// Roles on orthogonal resources overlap (round-8 proven). Split rebalanced 1:2
// (place is latency/atomic-bound and was finishing early at 1:1; convert is the
// 307MB streaming limiter). Place-role rank `sub` keeps sub&7 == blockIdx&7 == XCD,
// so cell (g=(e>>8)&7) counters/slabs are only touched by XCD g.

__global__ void place_conv(const int* __restrict__ sA, const int* __restrict__ dA,
                           const int* __restrict__ sB, const int* __restrict__ dB,
                           int* __restrict__ cnt, u32* __restrict__ binned,
                           int TBc, int NBA_, int E1, int Etot,
                           const float* __restrict__ xin, u16* __restrict__ xbf,
                           long long n4) {
    int grp = (int)blockIdx.x >> 3;                        // group of 8 blocks
    int lane8 = (int)blockIdx.x & 7;
    if (grp % 3 == 0) {
        // ---- place role: 1/3 of blocks (1024) ----
        int sub = (grp / 3) * 8 + lane8;                   // role-local rank, sub&7 == XCD
        int nplace = ((int)gridDim.x / 24) * 8;            // 1024
        int stride = nplace * (int)blockDim.x;             // 262144; >>8 %8==0: g invariant
        for (int e = sub * (int)blockDim.x + (int)threadIdx.x; e < Etot; e += stride) {
            int g = (e >> 8) & (NG - 1);                   // == sub&7 == this XCD
            int s, d, b;
            if (e < E1) {
                s = __builtin_nontemporal_load(sA + e);
                d = __builtin_nontemporal_load(dA + e);
                b = d >> LOG_RPB;
            } else {
                int e2 = e - E1;
                s = __builtin_nontemporal_load(sB + e2);
                d = __builtin_nontemporal_load(dB + e2);
                b = NBA_ + (d >> LOG_RPB);
            }
            int cell = g * TBc + b;
            int old = atomicAdd(&cnt[cell], 1);            // XCD-private counter
            if (old < CAP)
                binned[(long long)cell * CAP + old] = ((u32)s << LOG_RPB) | (u32)(d & (RPB - 1));
        }
    } else {
        // ---- convert role: 2/3 of blocks (2048): x_paper f32 -> bf16 ----
        int cg = grp - (grp / 3 + 1);                      // convert-local group index
        int sub = cg * 8 + lane8;
        long long nconv = ((long long)gridDim.x / 24) * 16;   // 2048
        long long stride = nconv * blockDim.x;
        for (long long i = (long long)sub * blockDim.x + threadIdx.x; i < n4; i += stride) {
            f32x4 v = __builtin_nontemporal_load((const f32x4*)xin + i);
            ushort4 o;
            o.x = f32_to_bf16_rne(v.x); o.y = f32_to_bf16_rne(v.y);
            o.z = f32_to_bf16_rne(v.z); o.w = f32_to_bf16_rne(v.w);
            *((ushort4*)xbf + i) = o;                      // re-read by gather1: cached
        }
    }
}

// ---------- gather hop: one block per bucket. Sort own bucket into LDS, then gather
// own 32 rows. Phase-4 loops are FULLY UNCONDITIONAL (clamped issue + masked-fma
// commit): any conditional def OR use of vv[] demotes it to scratch (rounds 11/12,
// rule #20). Proven register form from round 10. ----------

template <int BATCH, bool DBF>
__global__ void __launch_bounds__(256)
gather_hop(const u32* __restrict__ binned, const int* __restrict__ cnt,
           const u16* __restrict__ xv, void* __restrict__ outv,
           int TBc, int bucket_base, int n) {
    __shared__ int sed[BCAP];          // src ids, grouped by local row
    __shared__ int rp[RPB + 1];        // local row offsets into sed
    __shared__ int c[RPB];
    __shared__ int cur[RPB];

    int tid = (int)threadIdx.x;
    int b = bucket_base + (int)blockIdx.x;

    // --- phase 1: histogram of local-row ids over the 8 XCD slabs ---
    if (tid < RPB) c[tid] = 0;
    __syncthreads();
#pragma unroll
    for (int g = 0; g < NG; ++g) {
        int cell = g * TBc + b;
        int m = cnt[cell]; m = (m < CAP) ? m : CAP;
        long long base = (long long)cell * CAP;
        for (int i = tid; i < m; i += 256)
            atomicAdd(&c[binned[base + i] & (RPB - 1)], 1);
    }
    __syncthreads();
    // --- phase 2: tiny serial prefix (32 entries) ---
    if (tid == 0) {
        int run = 0;
        for (int r = 0; r < RPB; ++r) { cur[r] = run; rp[r] = run; run += c[r]; }
        rp[RPB] = run;
    }
    __syncthreads();
    // --- phase 3: place src ids grouped by local row (native LDS int atomics) ---
#pragma unroll
    for (int g = 0; g < NG; ++g) {
        int cell = g * TBc + b;
        int m = cnt[cell]; m = (m < CAP) ? m : CAP;
        long long base = (long long)cell * CAP;
        for (int i = tid; i < m; i += 256) {
            u32 e = binned[base + i];
            int pos = atomicAdd(&cur[e & (RPB - 1)], 1);
            sed[pos] = (int)(e >> LOG_RPB);
        }
    }
    __syncthreads();

    // --- phase 4: gather 32 rows; wave w owns rows w, w+4, ... ---
    int lane = tid & 63, w = tid >> 6;
    int row0 = (int)blockIdx.x * RPB;
    for (int rr = w; rr < RPB; rr += 4) {
        int row = row0 + rr;
        if (row >= n) break;
        int beg = rp[rr];
        int end = rp[rr + 1];
        float ax = 0.f, ay = 0.f, az = 0.f, aw = 0.f;
        for (int i = beg; i < end; i += BATCH) {
            int m = end - i;
            m = (m < BATCH) ? m : BATCH;                  // wave-uniform
            uint2 vv[BATCH];
#pragma unroll
            for (int j = 0; j < BATCH; ++j) {             // issue: ALL defs unconditional
                int jj = (j < m) ? j : (m - 1);           // clamp (dup loads = L1 hits)
                int s = sed[i + jj];                      // LDS broadcast (wave-uniform)
                vv[j] = *((const uint2*)(xv + (long long)s * DIM) + lane);
            }
#pragma unroll
            for (int j = 0; j < BATCH; ++j) {             // commit: ALL uses unconditional
                float mk = (j < m) ? 1.0f : 0.0f;         // masked fma (no branch)
                ax = fmaf(mk, __uint_as_float(vv[j].x << 16), ax);
                ay = fmaf(mk, __uint_as_float(vv[j].x & 0xFFFF0000u), ay);
                az = fmaf(mk, __uint_as_float(vv[j].y << 16), az);
                aw = fmaf(mk, __uint_as_float(vv[j].y & 0xFFFF0000u), aw);
            }
        }
        ax = fmaxf(ax, 0.f); ay = fmaxf(ay, 0.f); az = fmaxf(az, 0.f); aw = fmaxf(aw, 0.f);
        if (DBF) {
            ushort4 o;
            o.x = f32_to_bf16_rne(ax); o.y = f32_to_bf16_rne(ay);
            o.z = f32_to_bf16_rne(az); o.w = f32_to_bf16_rne(aw);
            *((ushort4*)outv + (long long)row * (DIM / 4) + lane) = o;  // re-read next hop
        } else {
            f32x4 o = { ax, ay, az, aw };
            __builtin_nontemporal_store(o, (f32x4*)outv + (long long)row * (DIM / 4) + lane);
        }
    }
}

// ---------- host ----------

extern "C" void kernel_launch(void* const* d_in, const int* in_sizes, int n_in,
                              void* d_out, int out_size, void* d_ws, size_t ws_size,
                              hipStream_t stream) {
    const float* x_paper = (const float*)d_in[0];
    const int* e_pa_src = (const int*)d_in[2];
    const int* e_pa_dst = (const int*)d_in[3];
    const int* e_ap_src = (const int*)d_in[4];
    const int* e_ap_dst = (const int*)d_in[5];

    const int nA = in_sizes[1] / DIM;         // 100000 authors (hop-1 dst, mean deg 10)
    const int nB = in_sizes[0] / DIM;         // 200000 papers  (hop-2 dst, mean deg 5)
    const int E1 = in_sizes[2];               // 1000000 (paper->author)
    const int E2 = in_sizes[4];               // 1000000 (author->paper)
    const int Etot = E1 + E2;

    const int NBA = (nA + RPB - 1) / RPB;     // 3125
    const int NBB = (nB + RPB - 1) / RPB;     // 6250
    const int TBc = NBA + NBB;                // 9375

    // ---- workspace (~192 MB) ----
    size_t off = 0;
    auto alloc = [&](size_t bytes) { size_t o = off; off += (bytes + 255) & ~(size_t)255; return o; };
    size_t o_xpbf   = alloc((size_t)nB * DIM * sizeof(u16));          // 102.4 MB
    size_t o_xa1    = alloc((size_t)nA * DIM * sizeof(u16));          // 51.2 MB
    size_t o_cnt    = alloc((size_t)NG * TBc * sizeof(int));          // 0.3 MB
    size_t o_binned = alloc((size_t)NG * TBc * CAP * sizeof(u32));    // 38.4 MB
    (void)ws_size;

    char* ws = (char*)d_ws;
    u16* xpbf   = (u16*)(ws + o_xpbf);
    u16* x_a1   = (u16*)(ws + o_xa1);
    int* cnt    = (int*)(ws + o_cnt);
    u32* binned = (u32*)(ws + o_binned);
    float* x_p2 = (float*)d_out;

    hipMemsetAsync(cnt, 0, (size_t)NG * TBc * sizeof(int), stream);

    long long n4 = (long long)nB * DIM / 4;
    place_conv<<<PC_B, 256, 0, stream>>>(
        e_pa_src, e_pa_dst, e_ap_src, e_ap_dst, cnt, binned,
        TBc, NBA, E1, Etot, x_paper, xpbf, n4);

    // hop 1: paper -> author, out = bf16(relu(sum)); BATCH=16 (mean degree 10)
    gather_hop<16, true><<<NBA, 256, 0, stream>>>(binned, cnt, xpbf, x_a1, TBc, 0, nA);

    // hop 2: author -> paper, out = f32 relu(sum), NT stores; BATCH=8 (mean degree 5)
    gather_hop<8, false><<<NBB, 256, 0, stream>>>(binned, cnt, x_a1, x_p2, TBc, NBA, nB);
}